// Round 1
// baseline (536.773 us; speedup 1.0000x reference)
//
#include <hip/hip_runtime.h>
#include <stdint.h>

#define BB 32
#define SS 512
#define DD 640
#define HH 10
#define DKK 64
#define NTOK (BB*SS)   // 16384

using f32x4  = __attribute__((ext_vector_type(4))) float;
using bf16x8 = __attribute__((ext_vector_type(8))) __bf16;
using u32x4  = __attribute__((ext_vector_type(4))) unsigned int;
using u16x4  = __attribute__((ext_vector_type(4))) unsigned short;
using i32x4  = __attribute__((ext_vector_type(4))) int;

__device__ inline unsigned short f2bf(float f){
  union { float f; unsigned int u; } v; v.f=f;
  unsigned int u=v.u;
  u += 0x7FFFu + ((u>>16)&1u);
  return (unsigned short)(u>>16);
}
__device__ inline float bf2f(unsigned short s){
  union { unsigned int u; float f; } v; v.u = ((unsigned int)s)<<16;
  return v.f;
}

// ---------------- conversions ----------------
__global__ void convert_qkv(const float* __restrict__ q, const float* __restrict__ k,
                            const float* __restrict__ v,
                            unsigned short* __restrict__ xq, unsigned short* __restrict__ xk,
                            unsigned short* __restrict__ xv){
  int i = blockIdx.x*blockDim.x + threadIdx.x;
  const int n4 = (NTOK*DD)/4;
  for (; i < n4; i += gridDim.x*blockDim.x){
    f32x4 a = ((const f32x4*)q)[i];
    f32x4 b = ((const f32x4*)k)[i];
    f32x4 c = ((const f32x4*)v)[i];
    u16x4 ra, rb, rc;
    #pragma unroll
    for (int j=0;j<4;j++){ ra[j]=f2bf(a[j]); rb[j]=f2bf(b[j]); rc[j]=f2bf(c[j]); }
    ((u16x4*)xq)[i]=ra; ((u16x4*)xk)[i]=rb; ((u16x4*)xv)[i]=rc;
  }
}

__global__ void convert_w(const float* __restrict__ wq, const float* __restrict__ wk,
                          const float* __restrict__ wv, const float* __restrict__ rw,
                          unsigned short* __restrict__ bwq, unsigned short* __restrict__ bwk,
                          unsigned short* __restrict__ bwv, unsigned short* __restrict__ brw,
                          unsigned short* __restrict__ brwt){
  int i = blockIdx.x*blockDim.x + threadIdx.x;
  if (i < DD*DD){
    bwq[i]=f2bf(wq[i]); bwk[i]=f2bf(wk[i]); bwv[i]=f2bf(wv[i]);
    unsigned short r = f2bf(rw[i]);
    brw[i]=r;
    int ri = i / DD, o = i % DD;
    brwt[o*DD + ri] = r;
  }
}

// bias[b,q,k] = mask ? adj/(layer+1) : -1e9   (bf16)
__global__ void bias_kernel(const int* __restrict__ mask, const float* __restrict__ adj,
                            const int* __restrict__ layer, unsigned short* __restrict__ bias){
  float sc = 1.0f/(float)(layer[0]+1);
  int i = blockIdx.x*blockDim.x + threadIdx.x;
  const int n4 = (BB*SS*SS)/4;
  for (; i < n4; i += gridDim.x*blockDim.x){
    i32x4 m = ((const i32x4*)mask)[i];
    f32x4 a = ((const f32x4*)adj)[i];
    u16x4 r;
    #pragma unroll
    for (int j=0;j<4;j++) r[j] = m[j] ? f2bf(a[j]*sc) : f2bf(-1e9f);
    ((u16x4*)bias)[i] = r;
  }
}

// ---------------- GEMM (NT, bf16 in, f32 acc) ----------------
// C[n,j] = sum_k A[n,k]*W[j,k] (+bias[j]); M=16384, N=640, K=640
// mode 0: out bf16 [b,h,s,dk];  mode 1: out bf16 [b,h,dk,s];  mode 2: out bf16 [n,j]*scale
#define BM 128
#define BN 128
#define BK 32

__global__ __launch_bounds__(256)
void gemm_nt(const unsigned short* __restrict__ A, const unsigned short* __restrict__ W,
             const float* __restrict__ bias, unsigned short* __restrict__ outp,
             int mode, float scale)
{
  __shared__ unsigned short As[BM][BK];
  __shared__ unsigned short Ws[BN][BK];
  const int tid  = threadIdx.x;
  const int m0   = blockIdx.x * BM;
  const int n0   = blockIdx.y * BN;
  const int lane = tid & 63;
  const int wave = tid >> 6;
  const int wr   = (wave >> 1) * 64;
  const int wc   = (wave & 1) * 64;
  const int l15  = lane & 15;
  const int g    = lane >> 4;

  f32x4 acc[4][4];
  #pragma unroll
  for (int i=0;i<4;i++)
    #pragma unroll
    for (int j=0;j<4;j++){ f32x4 z = {0.f,0.f,0.f,0.f}; acc[i][j]=z; }

  const int srow = tid >> 1;
  const int scol = (tid & 1) * 16;
  const unsigned short* Ag = A + (int64_t)(m0 + srow)*DD + scol;
  const unsigned short* Wg = W + (int64_t)(n0 + srow)*DD + scol;

  for (int k0 = 0; k0 < DD; k0 += BK){
    u32x4 av0 = *(const u32x4*)(Ag + k0);
    u32x4 av1 = *(const u32x4*)(Ag + k0 + 8);
    u32x4 wv0 = *(const u32x4*)(Wg + k0);
    u32x4 wv1 = *(const u32x4*)(Wg + k0 + 8);
    __syncthreads();
    *(u32x4*)&As[srow][scol]   = av0;
    *(u32x4*)&As[srow][scol+8] = av1;
    *(u32x4*)&Ws[srow][scol]   = wv0;
    *(u32x4*)&Ws[srow][scol+8] = wv1;
    __syncthreads();
    bf16x8 af[4], wf[4];
    #pragma unroll
    for (int m=0;m<4;m++) af[m] = *(const bf16x8*)&As[wr + m*16 + l15][g*8];
    #pragma unroll
    for (int n=0;n<4;n++) wf[n] = *(const bf16x8*)&Ws[wc + n*16 + l15][g*8];
    #pragma unroll
    for (int m=0;m<4;m++)
      #pragma unroll
      for (int n=0;n<4;n++)
        acc[m][n] = __builtin_amdgcn_mfma_f32_16x16x32_bf16(af[m], wf[n], acc[m][n], 0,0,0);
  }

  #pragma unroll
  for (int m=0;m<4;m++){
    const int rowbase = m0 + wr + m*16 + g*4;
    #pragma unroll
    for (int n=0;n<4;n++){
      const int col = n0 + wc + n*16 + l15;
      const float bv = bias ? bias[col] : 0.0f;
      #pragma unroll
      for (int r=0;r<4;r++){
        float val = acc[m][n][r] + bv;
        const int row = rowbase + r;
        if (mode == 0){
          int bb=row>>9, s=row&511, h=col>>6, dk=col&63;
          outp[(((int64_t)(bb*HH + h))*SS + s)*DKK + dk] = f2bf(val);
        } else if (mode == 1){
          int bb=row>>9, s=row&511, h=col>>6, dk=col&63;
          outp[(((int64_t)(bb*HH + h))*DKK + dk)*SS + s] = f2bf(val);
        } else {
          outp[(int64_t)row*DD + col] = f2bf(val*scale);
        }
      }
    }
  }
}

// ---------------- attention ----------------
// per block: (qtile of 64 rows, h, b). 4 waves x 16 q-rows. Q/K/V frags direct from
// global (NT, K-contiguous 16B). P kept in wave-private XOR-swizzled LDS rows.
__global__ __launch_bounds__(256)
void attn_kernel(const unsigned short* __restrict__ qb, const unsigned short* __restrict__ kb,
                 const unsigned short* __restrict__ vT, const unsigned short* __restrict__ bias,
                 unsigned short* __restrict__ xout)
{
  __shared__ unsigned short P[64*512];   // 64KB, row stride 1024B
  const int tid  = threadIdx.x;
  const int lane = tid & 63;
  const int wave = tid >> 6;
  const int l15  = lane & 15;
  const int g    = lane >> 4;

  const int qt = blockIdx.x;   // 0..7
  const int h  = blockIdx.y;   // 0..9
  const int b  = blockIdx.z;   // 0..31
  const int bh = b*HH + h;

  const unsigned short* Q  = qb + (int64_t)bh*SS*DKK;
  const unsigned short* K  = kb + (int64_t)bh*SS*DKK;
  const unsigned short* V  = vT + (int64_t)bh*DKK*SS;
  const unsigned short* Bs = bias + (int64_t)b*SS*SS;

  const int q0 = qt*64 + wave*16;     // wave's first q row (global in S)
  const int prow_base = wave*16;      // wave-private P rows

  bf16x8 qf[2];
  #pragma unroll
  for (int ks=0; ks<2; ks++)
    qf[ks] = *(const bf16x8*)(Q + (q0 + l15)*DKK + ks*32 + g*8);

  float lacc[4] = {0.f,0.f,0.f,0.f};

  for (int c = 0; c < 8; c++){         // 8 chunks of 64 k-columns
    f32x4 sc[4];
    #pragma unroll
    for (int j=0;j<4;j++){ f32x4 z={0.f,0.f,0.f,0.f}; sc[j]=z; }
    #pragma unroll
    for (int ks=0; ks<2; ks++){
      #pragma unroll
      for (int j=0;j<4;j++){
        bf16x8 kf = *(const bf16x8*)(K + (c*64 + j*16 + l15)*DKK + ks*32 + g*8);
        sc[j] = __builtin_amdgcn_mfma_f32_16x16x32_bf16(qf[ks], kf, sc[j], 0,0,0);
      }
    }
    #pragma unroll
    for (int j=0;j<4;j++){
      const int col = c*64 + j*16 + l15;
      #pragma unroll
      for (int r=0;r<4;r++){
        const int qrow = q0 + g*4 + r;
        float s = sc[j][r]*0.125f + bf2f(Bs[(int64_t)qrow*SS + col]);
        float p = __expf(s - 8.0f);          // fixed-max softmax (scores bounded)
        lacc[r] += p;
        const int prow = prow_base + g*4 + r;
        const int cb = col*2;
        const int sw = (cb>>4) ^ (prow & 7);
        *(unsigned short*)((char*)P + prow*1024 + sw*16 + (cb & 15)) = f2bf(p);
      }
    }
  }
  #pragma unroll
  for (int r=0;r<4;r++){
    float v = lacc[r];
    v += __shfl_xor(v, 1); v += __shfl_xor(v, 2);
    v += __shfl_xor(v, 4); v += __shfl_xor(v, 8);
    lacc[r] = 1.0f / v;
  }

  f32x4 oacc[4];
  #pragma unroll
  for (int n=0;n<4;n++){ f32x4 z={0.f,0.f,0.f,0.f}; oacc[n]=z; }
  for (int kt=0; kt<16; kt++){
    const int prow = prow_base + l15;
    const int cb = kt*64 + g*16;
    const int sw = (cb>>4) ^ (prow & 7);
    bf16x8 pf = *(const bf16x8*)((char*)P + prow*1024 + sw*16);
    #pragma unroll
    for (int n=0;n<4;n++){
      bf16x8 vf = *(const bf16x8*)(V + (n*16 + l15)*SS + kt*32 + g*8);
      oacc[n] = __builtin_amdgcn_mfma_f32_16x16x32_bf16(pf, vf, oacc[n], 0,0,0);
    }
  }
  #pragma unroll
  for (int n=0;n<4;n++){
    const int dk = n*16 + l15;
    #pragma unroll
    for (int r=0;r<4;r++){
      const int qrow = q0 + g*4 + r;
      const int ntok = b*SS + qrow;
      xout[(int64_t)ntok*DD + h*DKK + dk] = f2bf(oacc[n][r] * lacc[r]);
    }
  }
}

// ---------------- routing elementwise ----------------
// squash per token over 640; one wave per token
__global__ void squash_kernel(const unsigned short* __restrict__ sin,
                              unsigned short* __restrict__ bout,
                              float* __restrict__ fout, int final_out)
{
  const int widx = (blockIdx.x*blockDim.x + threadIdx.x) >> 6;
  const int lane = threadIdx.x & 63;
  if (widx >= NTOK) return;
  const unsigned short* row = sin + (int64_t)widx*DD;
  float v[10]; float sn = 0.f;
  #pragma unroll
  for (int i=0;i<10;i++){ v[i] = bf2f(row[i*64 + lane]); sn += v[i]*v[i]; }
  #pragma unroll
  for (int off=1; off<64; off<<=1) sn += __shfl_xor(sn, off);
  const float sc = (sn/(1.0f+sn)) * rsqrtf(sn + 1e-9f);
  if (final_out){
    float* o = fout + (int64_t)widx*DD;
    #pragma unroll
    for (int i=0;i<10;i++) o[i*64+lane] = v[i]*sc;
  } else {
    unsigned short* o = bout + (int64_t)widx*DD;
    #pragma unroll
    for (int i=0;i<10;i++) o[i*64+lane] = f2bf(v[i]*sc);
  }
}

// logits (+)= dot(priors_r, out) per (token, r); probs = softmax; xs = x*probs
__global__ void route_update(const unsigned short* __restrict__ x,
                             const unsigned short* __restrict__ gbuf,
                             float* __restrict__ logits,
                             unsigned short* __restrict__ xs, int first)
{
  const int widx = (blockIdx.x*blockDim.x + threadIdx.x) >> 6;
  const int lane = threadIdx.x & 63;
  if (widx >= NTOK) return;
  const unsigned short* xr = x + (int64_t)widx*DD;
  const unsigned short* gr = gbuf + (int64_t)widx*DD;
  float xv[10], dv[10];
  #pragma unroll
  for (int i=0;i<10;i++){
    xv[i] = bf2f(xr[i*64+lane]);
    dv[i] = xv[i]*bf2f(gr[i*64+lane]);
  }
  #pragma unroll
  for (int i=0;i<10;i++){
    float v = dv[i];
    #pragma unroll
    for (int off=1; off<64; off<<=1) v += __shfl_xor(v, off);
    dv[i] = v;
  }
  float* lrow = logits + widx*10;
  float lg[10];
  #pragma unroll
  for (int i=0;i<10;i++) lg[i] = first ? dv[i] : (lrow[i] + dv[i]);
  if (lane < 10) lrow[lane] = lg[lane];
  float mx = lg[0];
  #pragma unroll
  for (int i=1;i<10;i++) mx = fmaxf(mx, lg[i]);
  float se = 0.f;
  #pragma unroll
  for (int i=0;i<10;i++){ lg[i] = __expf(lg[i]-mx); se += lg[i]; }
  const float inv = 1.0f/se;
  unsigned short* xo = xs + (int64_t)widx*DD;
  #pragma unroll
  for (int i=0;i<10;i++) xo[i*64+lane] = f2bf(xv[i]*lg[i]*inv);
}

// ---------------- launch ----------------
extern "C" void kernel_launch(void* const* d_in, const int* in_sizes, int n_in,
                              void* d_out, int out_size, void* d_ws, size_t ws_size,
                              hipStream_t stream)
{
  (void)in_sizes; (void)n_in; (void)out_size; (void)ws_size;
  const float* q    = (const float*)d_in[0];
  const float* k    = (const float*)d_in[1];
  const float* v    = (const float*)d_in[2];
  const int*   mask = (const int*)d_in[3];
  const float* adj  = (const float*)d_in[4];
  const int*   layer= (const int*)d_in[5];
  const float* Wq   = (const float*)d_in[6];
  const float* bq   = (const float*)d_in[7];
  const float* Wk   = (const float*)d_in[8];
  const float* bk   = (const float*)d_in[9];
  const float* Wv   = (const float*)d_in[10];
  const float* bv   = (const float*)d_in[11];
  const float* rw   = (const float*)d_in[12];

  char* ws = (char*)d_ws;
  size_t off = 0;
  auto alloc = [&](size_t sz)->char*{ char* p = ws + off; off += (sz + 255) & ~(size_t)255; return p; };
  const size_t SZX = (size_t)NTOK*DD*2;
  unsigned short* Xq    = (unsigned short*)alloc(SZX);
  unsigned short* Xk    = (unsigned short*)alloc(SZX);
  unsigned short* Xv    = (unsigned short*)alloc(SZX);
  unsigned short* bWq   = (unsigned short*)alloc((size_t)DD*DD*2);
  unsigned short* bWk   = (unsigned short*)alloc((size_t)DD*DD*2);
  unsigned short* bWv   = (unsigned short*)alloc((size_t)DD*DD*2);
  unsigned short* bRW   = (unsigned short*)alloc((size_t)DD*DD*2);
  unsigned short* bRWT  = (unsigned short*)alloc((size_t)DD*DD*2);
  unsigned short* qbuf  = (unsigned short*)alloc(SZX);
  unsigned short* kbuf  = (unsigned short*)alloc(SZX);
  unsigned short* vTbuf = (unsigned short*)alloc(SZX);
  unsigned short* biasb = (unsigned short*)alloc((size_t)BB*SS*SS*2);
  unsigned short* xsb   = (unsigned short*)alloc(SZX);
  unsigned short* sbuf  = (unsigned short*)alloc(SZX);
  float*          logit = (float*)alloc((size_t)NTOK*10*4);
  // aliases (dead after projections)
  unsigned short* xout  = Xq;
  unsigned short* outit = Xk;
  unsigned short* gbuf  = Xv;

  convert_qkv<<<2048,256,0,stream>>>(q,k,v,Xq,Xk,Xv);
  convert_w<<<1600,256,0,stream>>>(Wq,Wk,Wv,rw,bWq,bWk,bWv,bRW,bRWT);
  bias_kernel<<<2048,256,0,stream>>>(mask,adj,layer,biasb);

  dim3 gg(NTOK/BM, DD/BN);
  gemm_nt<<<gg,256,0,stream>>>(Xq,bWq,bq,qbuf,0,1.0f);
  gemm_nt<<<gg,256,0,stream>>>(Xk,bWk,bk,kbuf,0,1.0f);
  gemm_nt<<<gg,256,0,stream>>>(Xv,bWv,bv,vTbuf,1,1.0f);

  dim3 ga(8, HH, BB);
  attn_kernel<<<ga,256,0,stream>>>(qbuf,kbuf,vTbuf,biasb,xout);

  // routing: it0
  gemm_nt<<<gg,256,0,stream>>>(xout,bRWT,nullptr,sbuf,2,0.1f);
  squash_kernel<<<4096,256,0,stream>>>(sbuf,outit,nullptr,0);
  gemm_nt<<<gg,256,0,stream>>>(outit,bRW,nullptr,gbuf,2,1.0f);
  route_update<<<4096,256,0,stream>>>(xout,gbuf,logit,xsb,1);
  // it1
  gemm_nt<<<gg,256,0,stream>>>(xsb,bRWT,nullptr,sbuf,2,1.0f);
  squash_kernel<<<4096,256,0,stream>>>(sbuf,outit,nullptr,0);
  gemm_nt<<<gg,256,0,stream>>>(outit,bRW,nullptr,gbuf,2,1.0f);
  route_update<<<4096,256,0,stream>>>(xout,gbuf,logit,xsb,0);
  // it2 (final)
  gemm_nt<<<gg,256,0,stream>>>(xsb,bRWT,nullptr,sbuf,2,1.0f);
  squash_kernel<<<4096,256,0,stream>>>(sbuf,nullptr,(float*)d_out,1);
}

// Round 3
// 526.111 us; speedup vs baseline: 1.0203x; 1.0203x over previous
//
#include <hip/hip_runtime.h>
#include <stdint.h>

#define BB 32
#define SS 512
#define DD 640
#define HH 10
#define DKK 64
#define NTOK (BB*SS)   // 16384

using f32x4  = __attribute__((ext_vector_type(4))) float;
using bf16x8 = __attribute__((ext_vector_type(8))) __bf16;
using u32x4  = __attribute__((ext_vector_type(4))) unsigned int;
using u32x2  = __attribute__((ext_vector_type(2))) unsigned int;
using u16x4  = __attribute__((ext_vector_type(4))) unsigned short;
using i32x4  = __attribute__((ext_vector_type(4))) int;

__device__ inline unsigned short f2bf(float f){
  union { float f; unsigned int u; } v; v.f=f;
  unsigned int u=v.u;
  u += 0x7FFFu + ((u>>16)&1u);
  return (unsigned short)(u>>16);
}
__device__ inline float bf2f(unsigned short s){
  union { unsigned int u; float f; } v; v.u = ((unsigned int)s)<<16;
  return v.f;
}

// ---------------- conversions ----------------
__global__ void convert_qkv(const float* __restrict__ q, const float* __restrict__ k,
                            const float* __restrict__ v,
                            unsigned short* __restrict__ xq, unsigned short* __restrict__ xk,
                            unsigned short* __restrict__ xv){
  int i = blockIdx.x*blockDim.x + threadIdx.x;
  const int n4 = (NTOK*DD)/4;
  for (; i < n4; i += gridDim.x*blockDim.x){
    f32x4 a = ((const f32x4*)q)[i];
    f32x4 b = ((const f32x4*)k)[i];
    f32x4 c = ((const f32x4*)v)[i];
    u16x4 ra, rb, rc;
    #pragma unroll
    for (int j=0;j<4;j++){ ra[j]=f2bf(a[j]); rb[j]=f2bf(b[j]); rc[j]=f2bf(c[j]); }
    ((u16x4*)xq)[i]=ra; ((u16x4*)xk)[i]=rb; ((u16x4*)xv)[i]=rc;
  }
}

__global__ void convert_w(const float* __restrict__ wq, const float* __restrict__ wk,
                          const float* __restrict__ wv, const float* __restrict__ rw,
                          unsigned short* __restrict__ bwq, unsigned short* __restrict__ bwk,
                          unsigned short* __restrict__ bwv, unsigned short* __restrict__ brw,
                          unsigned short* __restrict__ brwt){
  int i = blockIdx.x*blockDim.x + threadIdx.x;
  if (i < DD*DD){
    bwq[i]=f2bf(wq[i]); bwk[i]=f2bf(wk[i]); bwv[i]=f2bf(wv[i]);
    unsigned short r = f2bf(rw[i]);
    brw[i]=r;
    int ri = i / DD, o = i % DD;
    brwt[o*DD + ri] = r;
  }
}

// bias[b,q,k] = mask ? adj/(layer+1) : -1e9   (bf16)
__global__ void bias_kernel(const int* __restrict__ mask, const float* __restrict__ adj,
                            const int* __restrict__ layer, unsigned short* __restrict__ bias){
  float sc = 1.0f/(float)(layer[0]+1);
  int i = blockIdx.x*blockDim.x + threadIdx.x;
  const int n4 = (BB*SS*SS)/4;
  for (; i < n4; i += gridDim.x*blockDim.x){
    i32x4 m = ((const i32x4*)mask)[i];
    f32x4 a = ((const f32x4*)adj)[i];
    u16x4 r;
    #pragma unroll
    for (int j=0;j<4;j++) r[j] = m[j] ? f2bf(a[j]*sc) : f2bf(-1e9f);
    ((u16x4*)bias)[i] = r;
  }
}

// ---------------- GEMM (NT, bf16 in, f32 acc), m97-style global_load_lds ----
// C[n,j] = sum_k A[n,k]*W[j,k] (+bias[j]); M=16384, N=640, K=640
// mode 0: out bf16 [b,h,s,dk]; mode 1: out bf16 [b,h,dk,s]; mode 2: out bf16 [n,j]*scale
#define BM 128
#define BN 128
#define BK 32

__device__ inline void gload_lds16(const unsigned short* g, unsigned short* l){
  __builtin_amdgcn_global_load_lds(
      (const __attribute__((address_space(1))) unsigned int*)g,
      (__attribute__((address_space(3))) unsigned int*)l, 16, 0, 0);
}

__global__ __launch_bounds__(256)
void gemm_nt(const unsigned short* __restrict__ A, const unsigned short* __restrict__ W,
             const float* __restrict__ bias, unsigned short* __restrict__ outp,
             int mode, float scale)
{
  __shared__ unsigned short As[BM*BK];
  __shared__ unsigned short Ws[BN*BK];
  const int tid  = threadIdx.x;
  const int m0   = blockIdx.x * BM;
  const int n0   = blockIdx.y * BN;
  const int lane = tid & 63;
  const int wave = tid >> 6;
  const int wr   = (wave >> 1) * 64;
  const int wc   = (wave & 1) * 64;
  const int l15  = lane & 15;
  const int g    = lane >> 4;

  f32x4 acc[4][4];
  #pragma unroll
  for (int i=0;i<4;i++)
    #pragma unroll
    for (int j=0;j<4;j++){ f32x4 z = {0.f,0.f,0.f,0.f}; acc[i][j]=z; }

  // staging: wave covers 32 rows; lane -> row wave*32 + chunk*16 + (lane>>2),
  // k-octet (lane&3)*8. LDS dest linear: base + lane*16B (matches row-major [128][32]).
  const int srow = (lane >> 2);
  const int scol = (lane & 3) * 8;
  const unsigned short* Ag0 = A + (int64_t)(m0 + wave*32 + srow)*DD + scol;
  const unsigned short* Ag1 = A + (int64_t)(m0 + wave*32 + 16 + srow)*DD + scol;
  const unsigned short* Wg0 = W + (int64_t)(n0 + wave*32 + srow)*DD + scol;
  const unsigned short* Wg1 = W + (int64_t)(n0 + wave*32 + 16 + srow)*DD + scol;
  unsigned short* Al0 = As + wave*1024;
  unsigned short* Al1 = As + wave*1024 + 512;
  unsigned short* Wl0 = Ws + wave*1024;
  unsigned short* Wl1 = Ws + wave*1024 + 512;

  for (int k0 = 0; k0 < DD; k0 += BK){
    gload_lds16(Ag0 + k0, Al0);
    gload_lds16(Ag1 + k0, Al1);
    gload_lds16(Wg0 + k0, Wl0);
    gload_lds16(Wg1 + k0, Wl1);
    __syncthreads();                 // drains vmcnt -> LDS tiles ready
    bf16x8 af[4], wf[4];
    #pragma unroll
    for (int m=0;m<4;m++) af[m] = *(const bf16x8*)&As[(wr + m*16 + l15)*BK + g*8];
    #pragma unroll
    for (int n=0;n<4;n++) wf[n] = *(const bf16x8*)&Ws[(wc + n*16 + l15)*BK + g*8];
    #pragma unroll
    for (int m=0;m<4;m++)
      #pragma unroll
      for (int n=0;n<4;n++)
        acc[m][n] = __builtin_amdgcn_mfma_f32_16x16x32_bf16(af[m], wf[n], acc[m][n], 0,0,0);
    __syncthreads();                 // protect LDS before next-iter overwrite
  }

  #pragma unroll
  for (int m=0;m<4;m++){
    const int rowbase = m0 + wr + m*16 + g*4;
    #pragma unroll
    for (int n=0;n<4;n++){
      const int col = n0 + wc + n*16 + l15;
      const float bv = bias ? bias[col] : 0.0f;
      #pragma unroll
      for (int r=0;r<4;r++){
        float val = acc[m][n][r] + bv;
        const int row = rowbase + r;
        if (mode == 0){
          int bb=row>>9, s=row&511, h=col>>6, dk=col&63;
          outp[(((int64_t)(bb*HH + h))*SS + s)*DKK + dk] = f2bf(val);
        } else if (mode == 1){
          int bb=row>>9, s=row&511, h=col>>6, dk=col&63;
          outp[(((int64_t)(bb*HH + h))*DKK + dk)*SS + s] = f2bf(val);
        } else {
          outp[(int64_t)row*DD + col] = f2bf(val*scale);
        }
      }
    }
  }
}

// ---------------- attention ----------------
// block = (qtile 64 rows, h, b); 4 waves x 16 q-rows, wave-private, zero barriers.
// Transposed scores: mfma(K,Q) -> lane holds col=q(l15), rows=k(g*4+r): bias loads
// become 8B vectors, P written as packed 8B words. P chunked [16q x 64k]/wave (8KB LDS).
__global__ __launch_bounds__(256)
void attn_kernel(const unsigned short* __restrict__ qb, const unsigned short* __restrict__ kb,
                 const unsigned short* __restrict__ vT, const unsigned short* __restrict__ bias,
                 unsigned short* __restrict__ xout)
{
  __shared__ unsigned short P[4*16*64];   // per-wave [16 q][64 k], XOR-swizzled; 8KB
  const int tid  = threadIdx.x;
  const int lane = tid & 63;
  const int wave = tid >> 6;
  const int l15  = lane & 15;
  const int g    = lane >> 4;

  const int qt = blockIdx.x;   // 0..7
  const int h  = blockIdx.y;   // 0..9
  const int b  = blockIdx.z;   // 0..31
  const int bh = b*HH + h;

  const unsigned short* Q  = qb + (int64_t)bh*SS*DKK;
  const unsigned short* K  = kb + (int64_t)bh*SS*DKK;
  const unsigned short* V  = vT + (int64_t)bh*DKK*SS;
  const unsigned short* Bs = bias + (int64_t)b*SS*SS;

  const int q0 = qt*64 + wave*16;
  char* Pb = (char*)P + wave*2048;     // 16 rows x 128B

  bf16x8 qf[2];
  #pragma unroll
  for (int ks=0; ks<2; ks++)
    qf[ks] = *(const bf16x8*)(Q + (q0 + l15)*DKK + ks*32 + g*8);

  float lsum = 0.f;
  f32x4 oacc[4];
  #pragma unroll
  for (int n=0;n<4;n++){ f32x4 z={0.f,0.f,0.f,0.f}; oacc[n]=z; }

  for (int c = 0; c < 8; c++){           // 8 chunks of 64 k-cols
    f32x4 sc[4];
    #pragma unroll
    for (int j=0;j<4;j++){ f32x4 z={0.f,0.f,0.f,0.f}; sc[j]=z; }
    #pragma unroll
    for (int ks=0; ks<2; ks++){
      #pragma unroll
      for (int j=0;j<4;j++){
        bf16x8 kf = *(const bf16x8*)(K + (c*64 + j*16 + l15)*DKK + ks*32 + g*8);
        sc[j] = __builtin_amdgcn_mfma_f32_16x16x32_bf16(kf, qf[ks], sc[j], 0,0,0);
      }
    }
    // bias (8B vector) + exp + pack + 8B LDS write; scores: row=k=c*64+j*16+g*4+r, col=q=l15
    #pragma unroll
    for (int j=0;j<4;j++){
      u16x4 bv = *(const u16x4*)(Bs + (int64_t)(q0 + l15)*SS + c*64 + j*16 + g*4);
      float p[4];
      #pragma unroll
      for (int r=0;r<4;r++){
        float s = sc[j][r]*0.125f + bf2f(bv[r]);
        p[r] = __expf(s - 8.0f);          // fixed-max softmax (scores bounded)
        lsum += p[r];
      }
      unsigned int w0 = ((unsigned int)f2bf(p[1])<<16) | f2bf(p[0]);
      unsigned int w1 = ((unsigned int)f2bf(p[3])<<16) | f2bf(p[2]);
      const int kk = j*16 + g*4;          // 0..63 within chunk
      const int u  = kk >> 3;             // 16B unit 0..7
      const int sw = u ^ (l15 & 7);
      u32x2 w; w[0]=w0; w[1]=w1;
      *(u32x2*)(Pb + l15*128 + sw*16 + (kk&7)*2) = w;
    }
    // PV partial for this chunk (wave-private; compiler orders LDS write->read)
    #pragma unroll
    for (int kt=0; kt<2; kt++){
      const int u = kt*4 + g;
      bf16x8 pf = *(const bf16x8*)(Pb + l15*128 + (u ^ (l15&7))*16);
      #pragma unroll
      for (int n=0;n<4;n++){
        bf16x8 vf = *(const bf16x8*)(V + (n*16 + l15)*SS + c*64 + kt*32 + g*8);
        oacc[n] = __builtin_amdgcn_mfma_f32_16x16x32_bf16(pf, vf, oacc[n], 0,0,0);
      }
    }
  }

  // row sums: lane's lsum is partial for q=l15; reduce across the 4 g-groups
  lsum += __shfl_xor(lsum, 16);
  lsum += __shfl_xor(lsum, 32);
  const float inv = 1.0f / lsum;          // valid for q=l15
  float invr[4];
  #pragma unroll
  for (int r=0;r<4;r++) invr[r] = __shfl(inv, g*4 + r);   // inv for q=g*4+r

  #pragma unroll
  for (int n=0;n<4;n++){
    const int dk = n*16 + l15;
    #pragma unroll
    for (int r=0;r<4;r++){
      const int qrow = q0 + g*4 + r;
      const int ntok = b*SS + qrow;
      xout[(int64_t)ntok*DD + h*DKK + dk] = f2bf(oacc[n][r] * invr[r]);
    }
  }
}

// ---------------- routing elementwise ----------------
// squash per token over 640; one wave per token
__global__ void squash_kernel(const unsigned short* __restrict__ sin,
                              unsigned short* __restrict__ bout,
                              float* __restrict__ fout, int final_out)
{
  const int widx = (blockIdx.x*blockDim.x + threadIdx.x) >> 6;
  const int lane = threadIdx.x & 63;
  if (widx >= NTOK) return;
  const unsigned short* row = sin + (int64_t)widx*DD;
  float v[10]; float sn = 0.f;
  #pragma unroll
  for (int i=0;i<10;i++){ v[i] = bf2f(row[i*64 + lane]); sn += v[i]*v[i]; }
  #pragma unroll
  for (int off=1; off<64; off<<=1) sn += __shfl_xor(sn, off);
  const float sc = (sn/(1.0f+sn)) * rsqrtf(sn + 1e-9f);
  if (final_out){
    float* o = fout + (int64_t)widx*DD;
    #pragma unroll
    for (int i=0;i<10;i++) o[i*64+lane] = v[i]*sc;
  } else {
    unsigned short* o = bout + (int64_t)widx*DD;
    #pragma unroll
    for (int i=0;i<10;i++) o[i*64+lane] = f2bf(v[i]*sc);
  }
}

// logits (+)= dot(priors_r, out) per (token, r); probs = softmax; xs = x*probs (bf16)
__global__ void route_update(const unsigned short* __restrict__ x,
                             const unsigned short* __restrict__ gbuf,
                             float* __restrict__ logits,
                             unsigned short* __restrict__ xs, int first)
{
  const int widx = (blockIdx.x*blockDim.x + threadIdx.x) >> 6;
  const int lane = threadIdx.x & 63;
  if (widx >= NTOK) return;
  const unsigned short* xr = x + (int64_t)widx*DD;
  const unsigned short* gr = gbuf + (int64_t)widx*DD;
  float xv[10], dv[10];
  #pragma unroll
  for (int i=0;i<10;i++){
    xv[i] = bf2f(xr[i*64+lane]);
    dv[i] = xv[i]*bf2f(gr[i*64+lane]);
  }
  #pragma unroll
  for (int i=0;i<10;i++){
    float v = dv[i];
    #pragma unroll
    for (int off=1; off<64; off<<=1) v += __shfl_xor(v, off);
    dv[i] = v;
  }
  float* lrow = logits + widx*10;
  float lg[10];
  #pragma unroll
  for (int i=0;i<10;i++) lg[i] = first ? dv[i] : (lrow[i] + dv[i]);
  if (lane < 10) lrow[lane] = lg[lane];
  float mx = lg[0];
  #pragma unroll
  for (int i=1;i<10;i++) mx = fmaxf(mx, lg[i]);
  float se = 0.f;
  #pragma unroll
  for (int i=0;i<10;i++){ lg[i] = __expf(lg[i]-mx); se += lg[i]; }
  const float inv = 1.0f/se;
  unsigned short* xo = xs + (int64_t)widx*DD;
  #pragma unroll
  for (int i=0;i<10;i++) xo[i*64+lane] = f2bf(xv[i]*lg[i]*inv);
}

// ---------------- launch ----------------
extern "C" void kernel_launch(void* const* d_in, const int* in_sizes, int n_in,
                              void* d_out, int out_size, void* d_ws, size_t ws_size,
                              hipStream_t stream)
{
  (void)in_sizes; (void)n_in; (void)out_size; (void)ws_size;
  const float* q    = (const float*)d_in[0];
  const float* k    = (const float*)d_in[1];
  const float* v    = (const float*)d_in[2];
  const int*   mask = (const int*)d_in[3];
  const float* adj  = (const float*)d_in[4];
  const int*   layer= (const int*)d_in[5];
  const float* Wq   = (const float*)d_in[6];
  const float* bq   = (const float*)d_in[7];
  const float* Wk   = (const float*)d_in[8];
  const float* bk   = (const float*)d_in[9];
  const float* Wv   = (const float*)d_in[10];
  const float* bv   = (const float*)d_in[11];
  const float* rw   = (const float*)d_in[12];

  char* ws = (char*)d_ws;
  size_t off = 0;
  auto alloc = [&](size_t sz)->char*{ char* p = ws + off; off += (sz + 255) & ~(size_t)255; return p; };
  const size_t SZX = (size_t)NTOK*DD*2;
  unsigned short* Xq    = (unsigned short*)alloc(SZX);
  unsigned short* Xk    = (unsigned short*)alloc(SZX);
  unsigned short* Xv    = (unsigned short*)alloc(SZX);
  unsigned short* bWq   = (unsigned short*)alloc((size_t)DD*DD*2);
  unsigned short* bWk   = (unsigned short*)alloc((size_t)DD*DD*2);
  unsigned short* bWv   = (unsigned short*)alloc((size_t)DD*DD*2);
  unsigned short* bRW   = (unsigned short*)alloc((size_t)DD*DD*2);
  unsigned short* bRWT  = (unsigned short*)alloc((size_t)DD*DD*2);
  unsigned short* qbuf  = (unsigned short*)alloc(SZX);
  unsigned short* kbuf  = (unsigned short*)alloc(SZX);
  unsigned short* vTbuf = (unsigned short*)alloc(SZX);
  unsigned short* biasb = (unsigned short*)alloc((size_t)BB*SS*SS*2);
  unsigned short* xsb   = (unsigned short*)alloc(SZX);
  float*          logit = (float*)alloc((size_t)NTOK*10*4);
  // aliases (provably dead at reuse time, stream-ordered):
  unsigned short* xout  = Xq;    // Xq dead after q-projection
  unsigned short* outit = Xk;    // Xk dead after k-projection
  unsigned short* gbuf  = Xv;    // Xv dead after v-projection
  unsigned short* sbuf  = qbuf;  // qbuf dead after attention

  convert_qkv<<<2048,256,0,stream>>>(q,k,v,Xq,Xk,Xv);
  convert_w<<<1600,256,0,stream>>>(Wq,Wk,Wv,rw,bWq,bWk,bWv,bRW,bRWT);
  bias_kernel<<<2048,256,0,stream>>>(mask,adj,layer,biasb);

  dim3 gg(NTOK/BM, DD/BN);
  gemm_nt<<<gg,256,0,stream>>>(Xq,bWq,bq,qbuf,0,1.0f);
  gemm_nt<<<gg,256,0,stream>>>(Xk,bWk,bk,kbuf,0,1.0f);
  gemm_nt<<<gg,256,0,stream>>>(Xv,bWv,bv,vTbuf,1,1.0f);

  dim3 ga(8, HH, BB);
  attn_kernel<<<ga,256,0,stream>>>(qbuf,kbuf,vTbuf,biasb,xout);

  // routing: it0 (uniform probs 1/10 folded into scale)
  gemm_nt<<<gg,256,0,stream>>>(xout,bRWT,nullptr,sbuf,2,0.1f);
  squash_kernel<<<4096,256,0,stream>>>(sbuf,outit,nullptr,0);
  gemm_nt<<<gg,256,0,stream>>>(outit,bRW,nullptr,gbuf,2,1.0f);
  route_update<<<4096,256,0,stream>>>(xout,gbuf,logit,xsb,1);
  // it1
  gemm_nt<<<gg,256,0,stream>>>(xsb,bRWT,nullptr,sbuf,2,1.0f);
  squash_kernel<<<4096,256,0,stream>>>(sbuf,outit,nullptr,0);
  gemm_nt<<<gg,256,0,stream>>>(outit,bRW,nullptr,gbuf,2,1.0f);
  route_update<<<4096,256,0,stream>>>(xout,gbuf,logit,xsb,0);
  // it2 (final)
  gemm_nt<<<gg,256,0,stream>>>(xsb,bRWT,nullptr,sbuf,2,1.0f);
  squash_kernel<<<4096,256,0,stream>>>(sbuf,nullptr,(float*)d_out,1);
}

// Round 4
// 423.940 us; speedup vs baseline: 1.2662x; 1.2410x over previous
//
#include <hip/hip_runtime.h>
#include <stdint.h>

#define BB 32
#define SS 512
#define DD 640
#define HH 10
#define DKK 64
#define NTOK (BB*SS)   // 16384

using f32x4  = __attribute__((ext_vector_type(4))) float;
using bf16x8 = __attribute__((ext_vector_type(8))) __bf16;
using u32x4  = __attribute__((ext_vector_type(4))) unsigned int;
using u32x2  = __attribute__((ext_vector_type(2))) unsigned int;
using u16x4  = __attribute__((ext_vector_type(4))) unsigned short;
using i32x4  = __attribute__((ext_vector_type(4))) int;

__device__ inline unsigned short f2bf(float f){
  union { float f; unsigned int u; } v; v.f=f;
  unsigned int u=v.u;
  u += 0x7FFFu + ((u>>16)&1u);
  return (unsigned short)(u>>16);
}
__device__ inline float bf2f(unsigned short s){
  union { unsigned int u; float f; } v; v.u = ((unsigned int)s)<<16;
  return v.f;
}
__device__ inline unsigned int cvtpk_bf16(float lo, float hi){
  unsigned int r;
  asm volatile("v_cvt_pk_bf16_f32 %0, %1, %2" : "=v"(r) : "v"(lo), "v"(hi));
  return r;
}

// ---------------- conversions ----------------
__global__ void convert_qkv(const float* __restrict__ q, const float* __restrict__ k,
                            const float* __restrict__ v,
                            unsigned short* __restrict__ xq, unsigned short* __restrict__ xk,
                            unsigned short* __restrict__ xv){
  int i = blockIdx.x*blockDim.x + threadIdx.x;
  const int n4 = (NTOK*DD)/4;
  for (; i < n4; i += gridDim.x*blockDim.x){
    f32x4 a = ((const f32x4*)q)[i];
    f32x4 b = ((const f32x4*)k)[i];
    f32x4 c = ((const f32x4*)v)[i];
    u16x4 ra, rb, rc;
    #pragma unroll
    for (int j=0;j<4;j++){ ra[j]=f2bf(a[j]); rb[j]=f2bf(b[j]); rc[j]=f2bf(c[j]); }
    ((u16x4*)xq)[i]=ra; ((u16x4*)xk)[i]=rb; ((u16x4*)xv)[i]=rc;
  }
}

__global__ void convert_w(const float* __restrict__ wq, const float* __restrict__ wk,
                          const float* __restrict__ wv, const float* __restrict__ rw,
                          unsigned short* __restrict__ bwq, unsigned short* __restrict__ bwk,
                          unsigned short* __restrict__ bwv, unsigned short* __restrict__ brw,
                          unsigned short* __restrict__ brwt){
  int i = blockIdx.x*blockDim.x + threadIdx.x;
  if (i < DD*DD){
    bwq[i]=f2bf(wq[i]); bwk[i]=f2bf(wk[i]); bwv[i]=f2bf(wv[i]);
    unsigned short r = f2bf(rw[i]);
    brw[i]=r;
    int ri = i / DD, o = i % DD;
    brwt[o*DD + ri] = r;
  }
}

// bias in 16x16-tile layout: biasT[((b*32 + q>>4)*32 + k>>4)*256 + (q&15)*16 + (k&15)]
__global__ void bias_kernel(const int* __restrict__ mask, const float* __restrict__ adj,
                            const int* __restrict__ layer, unsigned short* __restrict__ biasT){
  float sc = 1.0f/(float)(layer[0]+1);
  int i = blockIdx.x*blockDim.x + threadIdx.x;
  const int n4 = (BB*SS*SS)/4;
  for (; i < n4; i += gridDim.x*blockDim.x){
    i32x4 m = ((const i32x4*)mask)[i];
    f32x4 a = ((const f32x4*)adj)[i];
    u16x4 r;
    #pragma unroll
    for (int j=0;j<4;j++) r[j] = m[j] ? f2bf(a[j]*sc) : f2bf(-1e9f);
    const int e  = i*4;
    const int bb = e >> 18;
    const int qq = (e >> 9) & 511;
    const int kk = e & 511;
    const int idx = (((bb*32 + (qq>>4))*32 + (kk>>4))<<8) + ((qq&15)<<4) + (kk&15);
    *(u16x4*)(biasT + idx) = r;
  }
}

// ---------------- GEMM (NT, bf16 in, f32 acc), gload_lds + double buffer ----
// C[n,j] = sum_k A[n,k]*W[j,k] (+bias[j]); M=16384, N=640, K=640
// mode 0: out bf16 [b,h,s,dk]; mode 1: out bf16 [b,h,dk,s]; mode 2: out bf16 [n,j]*scale
#define BM 128
#define BN 128
#define BK 32

__device__ inline void gload_lds16(const unsigned short* g, unsigned short* l){
  __builtin_amdgcn_global_load_lds(
      (const __attribute__((address_space(1))) unsigned int*)g,
      (__attribute__((address_space(3))) unsigned int*)l, 16, 0, 0);
}

__global__ __launch_bounds__(256)
void gemm_nt(const unsigned short* __restrict__ A, const unsigned short* __restrict__ W,
             const float* __restrict__ bias, unsigned short* __restrict__ outp,
             int mode, float scale)
{
  __shared__ unsigned short As[2][BM*BK];
  __shared__ unsigned short Ws[2][BN*BK];
  const int tid  = threadIdx.x;
  const int m0   = blockIdx.x * BM;
  const int n0   = blockIdx.y * BN;
  const int lane = tid & 63;
  const int wave = tid >> 6;
  const int wr   = (wave >> 1) * 64;
  const int wc   = (wave & 1) * 64;
  const int l15  = lane & 15;
  const int g    = lane >> 4;

  f32x4 acc[4][4];
  #pragma unroll
  for (int i=0;i<4;i++)
    #pragma unroll
    for (int j=0;j<4;j++){ f32x4 z = {0.f,0.f,0.f,0.f}; acc[i][j]=z; }

  const int srow = (lane >> 2);
  const int scol = (lane & 3) * 8;
  const unsigned short* Ag0 = A + (int64_t)(m0 + wave*32 + srow)*DD + scol;
  const unsigned short* Ag1 = A + (int64_t)(m0 + wave*32 + 16 + srow)*DD + scol;
  const unsigned short* Wg0 = W + (int64_t)(n0 + wave*32 + srow)*DD + scol;
  const unsigned short* Wg1 = W + (int64_t)(n0 + wave*32 + 16 + srow)*DD + scol;

  auto stage = [&](int buf, int k0){
    gload_lds16(Ag0 + k0, As[buf] + wave*1024);
    gload_lds16(Ag1 + k0, As[buf] + wave*1024 + 512);
    gload_lds16(Wg0 + k0, Ws[buf] + wave*1024);
    gload_lds16(Wg1 + k0, Ws[buf] + wave*1024 + 512);
  };

  stage(0, 0);
  int it = 0;
  for (int k0 = 0; k0 < DD; k0 += BK, it++){
    const int buf = it & 1;
    __syncthreads();               // stage(buf) complete; prev readers of buf^1 done
    if (k0 + BK < DD) stage(buf^1, k0 + BK);
    bf16x8 af[4], wf[4];
    #pragma unroll
    for (int m=0;m<4;m++) af[m] = *(const bf16x8*)&As[buf][(wr + m*16 + l15)*BK + g*8];
    #pragma unroll
    for (int n=0;n<4;n++) wf[n] = *(const bf16x8*)&Ws[buf][(wc + n*16 + l15)*BK + g*8];
    #pragma unroll
    for (int m=0;m<4;m++)
      #pragma unroll
      for (int n=0;n<4;n++)
        acc[m][n] = __builtin_amdgcn_mfma_f32_16x16x32_bf16(af[m], wf[n], acc[m][n], 0,0,0);
  }

  #pragma unroll
  for (int m=0;m<4;m++){
    const int rowbase = m0 + wr + m*16 + g*4;
    #pragma unroll
    for (int n=0;n<4;n++){
      const int col = n0 + wc + n*16 + l15;
      const float bv = bias ? bias[col] : 0.0f;
      #pragma unroll
      for (int r=0;r<4;r++){
        float val = acc[m][n][r] + bv;
        const int row = rowbase + r;
        if (mode == 0){
          int bb=row>>9, s=row&511, h=col>>6, dk=col&63;
          outp[(((int64_t)(bb*HH + h))*SS + s)*DKK + dk] = f2bf(val);
        } else if (mode == 1){
          int bb=row>>9, s=row&511, h=col>>6, dk=col&63;
          outp[(((int64_t)(bb*HH + h))*DKK + dk)*SS + s] = f2bf(val);
        } else {
          outp[(int64_t)row*DD + col] = f2bf(val*scale);
        }
      }
    }
  }
}

// ---------------- attention ----------------
// block=(qt64,h,b), 4 waves x 16 q-rows. K/V chunks staged in LDS via gload_lds
// (pre-swizzled global source -> XOR-swizzled LDS), double-buffered, shared by waves.
// Transposed-score mfma(K,Q); bias from tiled layout (dense 512B reads); P wave-private.
__global__ __launch_bounds__(256)
void attn_kernel(const unsigned short* __restrict__ qb, const unsigned short* __restrict__ kb,
                 const unsigned short* __restrict__ vT, const unsigned short* __restrict__ biasT,
                 unsigned short* __restrict__ xout)
{
  __shared__ unsigned short SH[20480];   // 40KB: K 2x8KB | V 2x8KB | P 4x2KB
  unsigned short* Kl = SH;               // [2][4096]
  unsigned short* Vl = SH + 8192;        // [2][4096]
  char* Pall = (char*)(SH + 16384);

  const int tid  = threadIdx.x;
  const int lane = tid & 63;
  const int wave = tid >> 6;
  const int l15  = lane & 15;
  const int g    = lane >> 4;

  const int qt = blockIdx.x;   // 0..7
  const int h  = blockIdx.y;   // 0..9
  const int b  = blockIdx.z;   // 0..31
  const int bh = b*HH + h;

  const unsigned short* Q  = qb + (int64_t)bh*SS*DKK;
  const unsigned short* K  = kb + (int64_t)bh*SS*DKK;
  const unsigned short* V  = vT + (int64_t)bh*DKK*SS;
  const unsigned short* Bt = biasT + (int64_t)((b*32 + qt*4 + wave)*32)*256;

  const int q0 = qt*64 + wave*16;
  char* Pb = Pall + wave*2048;           // 16 rows x 128B

  // staging: per gload call, lane covers LDS unit (lane*16B): row=i*8+(lane>>3),
  // unit-in-row=lane&7 which holds logical col16 = (lane&7)^(row&7)
  const int srow8 = lane >> 3;
  const int sunit = (lane & 7) ^ (srow8 & 7);

  bf16x8 qf[2];
  #pragma unroll
  for (int ks=0; ks<2; ks++)
    qf[ks] = *(const bf16x8*)(Q + (q0 + l15)*DKK + ks*32 + g*8);

  auto stage = [&](int c, int buf){
    #pragma unroll
    for (int c2=0;c2<2;c2++){
      const int i = wave*2 + c2;                      // 0..7 across waves
      gload_lds16(K + (int64_t)(c*64 + i*8 + srow8)*DKK + sunit*8,
                  Kl + buf*4096 + i*512);
      gload_lds16(V + (int64_t)(i*8 + srow8)*SS + c*64 + sunit*8,
                  Vl + buf*4096 + i*512);
    }
  };

  float lsum = 0.f;
  f32x4 oacc[4];
  #pragma unroll
  for (int n=0;n<4;n++){ f32x4 z={0.f,0.f,0.f,0.f}; oacc[n]=z; }

  stage(0, 0);
  for (int c = 0; c < 8; c++){
    const int buf = c & 1;
    __syncthreads();                     // stage(c) landed; buf^1 readers done
    if (c < 7) stage(c+1, buf^1);

    // bias for chunk c: 4 x 8B, lanes dense over 512B per (c,j) tile
    u16x4 bv[4];
    #pragma unroll
    for (int j=0;j<4;j++)
      bv[j] = *(const u16x4*)(Bt + (c*4 + j)*256 + l15*16 + g*4);

    f32x4 sc[4];
    #pragma unroll
    for (int j=0;j<4;j++){ f32x4 z={0.f,0.f,0.f,0.f}; sc[j]=z; }
    #pragma unroll
    for (int ks=0; ks<2; ks++){
      #pragma unroll
      for (int j=0;j<4;j++){
        bf16x8 kf = *(const bf16x8*)((char*)(Kl + buf*4096)
                     + (j*16 + l15)*128 + (((ks*4+g) ^ (l15&7))*16));
        sc[j] = __builtin_amdgcn_mfma_f32_16x16x32_bf16(kf, qf[ks], sc[j], 0,0,0);
      }
    }
    // softmax partial: row=k=c*64+j*16+g*4+r, col=q=l15
    #pragma unroll
    for (int j=0;j<4;j++){
      float p[4];
      #pragma unroll
      for (int r=0;r<4;r++){
        float s = __builtin_fmaf(sc[j][r], 0.125f, bf2f(bv[j][r]));
        p[r] = __expf(s - 8.0f);
        lsum += p[r];
      }
      unsigned int w0 = cvtpk_bf16(p[0], p[1]);
      unsigned int w1 = cvtpk_bf16(p[2], p[3]);
      const int kk = j*16 + g*4;
      const int sw = (kk >> 3) ^ (l15 & 7);
      u32x2 w; w[0]=w0; w[1]=w1;
      *(u32x2*)(Pb + l15*128 + sw*16 + (kk&7)*2) = w;
    }
    // PV for this chunk
    #pragma unroll
    for (int kt=0; kt<2; kt++){
      bf16x8 pf = *(const bf16x8*)(Pb + l15*128 + (((kt*4+g) ^ (l15&7))*16));
      #pragma unroll
      for (int n=0;n<4;n++){
        bf16x8 vf = *(const bf16x8*)((char*)(Vl + buf*4096)
                     + (n*16 + l15)*128 + (((kt*4+g) ^ (l15&7))*16));
        oacc[n] = __builtin_amdgcn_mfma_f32_16x16x32_bf16(pf, vf, oacc[n], 0,0,0);
      }
    }
  }

  // row sums: lane's lsum is partial for q=l15; reduce across the 4 g-groups
  lsum += __shfl_xor(lsum, 16);
  lsum += __shfl_xor(lsum, 32);
  const float inv = 1.0f / lsum;          // valid for q=l15
  float invr[4];
  #pragma unroll
  for (int r=0;r<4;r++) invr[r] = __shfl(inv, g*4 + r);

  #pragma unroll
  for (int n=0;n<4;n++){
    const int dk = n*16 + l15;
    #pragma unroll
    for (int r=0;r<4;r++){
      const int qrow = q0 + g*4 + r;
      const int ntok = b*SS + qrow;
      xout[(int64_t)ntok*DD + h*DKK + dk] = f2bf(oacc[n][r] * invr[r]);
    }
  }
}

// ---------------- routing elementwise ----------------
__global__ void squash_kernel(const unsigned short* __restrict__ sin,
                              unsigned short* __restrict__ bout,
                              float* __restrict__ fout, int final_out)
{
  const int widx = (blockIdx.x*blockDim.x + threadIdx.x) >> 6;
  const int lane = threadIdx.x & 63;
  if (widx >= NTOK) return;
  const unsigned short* row = sin + (int64_t)widx*DD;
  float v[10]; float sn = 0.f;
  #pragma unroll
  for (int i=0;i<10;i++){ v[i] = bf2f(row[i*64 + lane]); sn += v[i]*v[i]; }
  #pragma unroll
  for (int off=1; off<64; off<<=1) sn += __shfl_xor(sn, off);
  const float sc = (sn/(1.0f+sn)) * rsqrtf(sn + 1e-9f);
  if (final_out){
    float* o = fout + (int64_t)widx*DD;
    #pragma unroll
    for (int i=0;i<10;i++) o[i*64+lane] = v[i]*sc;
  } else {
    unsigned short* o = bout + (int64_t)widx*DD;
    #pragma unroll
    for (int i=0;i<10;i++) o[i*64+lane] = f2bf(v[i]*sc);
  }
}

__global__ void route_update(const unsigned short* __restrict__ x,
                             const unsigned short* __restrict__ gbuf,
                             float* __restrict__ logits,
                             unsigned short* __restrict__ xs, int first)
{
  const int widx = (blockIdx.x*blockDim.x + threadIdx.x) >> 6;
  const int lane = threadIdx.x & 63;
  if (widx >= NTOK) return;
  const unsigned short* xr = x + (int64_t)widx*DD;
  const unsigned short* gr = gbuf + (int64_t)widx*DD;
  float xv[10], dv[10];
  #pragma unroll
  for (int i=0;i<10;i++){
    xv[i] = bf2f(xr[i*64+lane]);
    dv[i] = xv[i]*bf2f(gr[i*64+lane]);
  }
  #pragma unroll
  for (int i=0;i<10;i++){
    float v = dv[i];
    #pragma unroll
    for (int off=1; off<64; off<<=1) v += __shfl_xor(v, off);
    dv[i] = v;
  }
  float* lrow = logits + widx*10;
  float lg[10];
  #pragma unroll
  for (int i=0;i<10;i++) lg[i] = first ? dv[i] : (lrow[i] + dv[i]);
  if (lane < 10) lrow[lane] = lg[lane];
  float mx = lg[0];
  #pragma unroll
  for (int i=1;i<10;i++) mx = fmaxf(mx, lg[i]);
  float se = 0.f;
  #pragma unroll
  for (int i=0;i<10;i++){ lg[i] = __expf(lg[i]-mx); se += lg[i]; }
  const float inv = 1.0f/se;
  unsigned short* xo = xs + (int64_t)widx*DD;
  #pragma unroll
  for (int i=0;i<10;i++) xo[i*64+lane] = f2bf(xv[i]*lg[i]*inv);
}

// ---------------- launch ----------------
extern "C" void kernel_launch(void* const* d_in, const int* in_sizes, int n_in,
                              void* d_out, int out_size, void* d_ws, size_t ws_size,
                              hipStream_t stream)
{
  (void)in_sizes; (void)n_in; (void)out_size; (void)ws_size;
  const float* q    = (const float*)d_in[0];
  const float* k    = (const float*)d_in[1];
  const float* v    = (const float*)d_in[2];
  const int*   mask = (const int*)d_in[3];
  const float* adj  = (const float*)d_in[4];
  const int*   layer= (const int*)d_in[5];
  const float* Wq   = (const float*)d_in[6];
  const float* bq   = (const float*)d_in[7];
  const float* Wk   = (const float*)d_in[8];
  const float* bk   = (const float*)d_in[9];
  const float* Wv   = (const float*)d_in[10];
  const float* bv   = (const float*)d_in[11];
  const float* rw   = (const float*)d_in[12];

  char* ws = (char*)d_ws;
  size_t off = 0;
  auto alloc = [&](size_t sz)->char*{ char* p = ws + off; off += (sz + 255) & ~(size_t)255; return p; };
  const size_t SZX = (size_t)NTOK*DD*2;
  unsigned short* Xq    = (unsigned short*)alloc(SZX);
  unsigned short* Xk    = (unsigned short*)alloc(SZX);
  unsigned short* Xv    = (unsigned short*)alloc(SZX);
  unsigned short* bWq   = (unsigned short*)alloc((size_t)DD*DD*2);
  unsigned short* bWk   = (unsigned short*)alloc((size_t)DD*DD*2);
  unsigned short* bWv   = (unsigned short*)alloc((size_t)DD*DD*2);
  unsigned short* bRW   = (unsigned short*)alloc((size_t)DD*DD*2);
  unsigned short* bRWT  = (unsigned short*)alloc((size_t)DD*DD*2);
  unsigned short* qbuf  = (unsigned short*)alloc(SZX);
  unsigned short* kbuf  = (unsigned short*)alloc(SZX);
  unsigned short* vTbuf = (unsigned short*)alloc(SZX);
  unsigned short* biasb = (unsigned short*)alloc((size_t)BB*SS*SS*2);
  unsigned short* xsb   = (unsigned short*)alloc(SZX);
  float*          logit = (float*)alloc((size_t)NTOK*10*4);
  // aliases (provably dead at reuse time, stream-ordered):
  unsigned short* xout  = Xq;    // Xq dead after q-projection
  unsigned short* outit = Xk;    // Xk dead after k-projection
  unsigned short* gbuf  = Xv;    // Xv dead after v-projection
  unsigned short* sbuf  = qbuf;  // qbuf dead after attention

  convert_qkv<<<2048,256,0,stream>>>(q,k,v,Xq,Xk,Xv);
  convert_w<<<1600,256,0,stream>>>(Wq,Wk,Wv,rw,bWq,bWk,bWv,bRW,bRWT);
  bias_kernel<<<2048,256,0,stream>>>(mask,adj,layer,biasb);

  dim3 gg(NTOK/BM, DD/BN);
  gemm_nt<<<gg,256,0,stream>>>(Xq,bWq,bq,qbuf,0,1.0f);
  gemm_nt<<<gg,256,0,stream>>>(Xk,bWk,bk,kbuf,0,1.0f);
  gemm_nt<<<gg,256,0,stream>>>(Xv,bWv,bv,vTbuf,1,1.0f);

  dim3 ga(8, HH, BB);
  attn_kernel<<<ga,256,0,stream>>>(qbuf,kbuf,vTbuf,biasb,xout);

  // routing: it0 (uniform probs 1/10 folded into scale)
  gemm_nt<<<gg,256,0,stream>>>(xout,bRWT,nullptr,sbuf,2,0.1f);
  squash_kernel<<<4096,256,0,stream>>>(sbuf,outit,nullptr,0);
  gemm_nt<<<gg,256,0,stream>>>(outit,bRW,nullptr,gbuf,2,1.0f);
  route_update<<<4096,256,0,stream>>>(xout,gbuf,logit,xsb,1);
  // it1
  gemm_nt<<<gg,256,0,stream>>>(xsb,bRWT,nullptr,sbuf,2,1.0f);
  squash_kernel<<<4096,256,0,stream>>>(sbuf,outit,nullptr,0);
  gemm_nt<<<gg,256,0,stream>>>(outit,bRW,nullptr,gbuf,2,1.0f);
  route_update<<<4096,256,0,stream>>>(xout,gbuf,logit,xsb,0);
  // it2 (final)
  gemm_nt<<<gg,256,0,stream>>>(xsb,bRWT,nullptr,sbuf,2,1.0f);
  squash_kernel<<<4096,256,0,stream>>>(sbuf,nullptr,(float*)d_out,1);
}

// Round 5
// 360.945 us; speedup vs baseline: 1.4871x; 1.1745x over previous
//
#include <hip/hip_runtime.h>
#include <stdint.h>

#define BB 32
#define SS 512
#define DD 640
#define HH 10
#define DKK 64
#define NTOK (BB*SS)   // 16384

using f32x4  = __attribute__((ext_vector_type(4))) float;
using bf16x8 = __attribute__((ext_vector_type(8))) __bf16;
using u32x4  = __attribute__((ext_vector_type(4))) unsigned int;
using u32x2  = __attribute__((ext_vector_type(2))) unsigned int;
using u16x4  = __attribute__((ext_vector_type(4))) unsigned short;
using i32x4  = __attribute__((ext_vector_type(4))) int;

__device__ inline unsigned short f2bf(float f){
  union { float f; unsigned int u; } v; v.f=f;
  unsigned int u=v.u;
  u += 0x7FFFu + ((u>>16)&1u);
  return (unsigned short)(u>>16);
}
__device__ inline float bf2f(unsigned short s){
  union { unsigned int u; float f; } v; v.u = ((unsigned int)s)<<16;
  return v.f;
}
__device__ inline unsigned int cvtpk_bf16(float lo, float hi){
  unsigned int r;
  asm volatile("v_cvt_pk_bf16_f32 %0, %1, %2" : "=v"(r) : "v"(lo), "v"(hi));
  return r;
}

// ---------------- conversions ----------------
__global__ void convert_qkv(const float* __restrict__ q, const float* __restrict__ k,
                            const float* __restrict__ v,
                            unsigned short* __restrict__ xq, unsigned short* __restrict__ xk,
                            unsigned short* __restrict__ xv){
  int i = blockIdx.x*blockDim.x + threadIdx.x;
  const int n4 = (NTOK*DD)/4;
  for (; i < n4; i += gridDim.x*blockDim.x){
    f32x4 a = ((const f32x4*)q)[i];
    f32x4 b = ((const f32x4*)k)[i];
    f32x4 c = ((const f32x4*)v)[i];
    u16x4 ra, rb, rc;
    #pragma unroll
    for (int j=0;j<4;j++){ ra[j]=f2bf(a[j]); rb[j]=f2bf(b[j]); rc[j]=f2bf(c[j]); }
    ((u16x4*)xq)[i]=ra; ((u16x4*)xk)[i]=rb; ((u16x4*)xv)[i]=rc;
  }
}

__global__ void convert_w(const float* __restrict__ wq, const float* __restrict__ wk,
                          const float* __restrict__ wv, const float* __restrict__ rw,
                          unsigned short* __restrict__ bwq, unsigned short* __restrict__ bwk,
                          unsigned short* __restrict__ bwv, unsigned short* __restrict__ brw,
                          unsigned short* __restrict__ brwt){
  int i = blockIdx.x*blockDim.x + threadIdx.x;
  if (i < DD*DD){
    bwq[i]=f2bf(wq[i]); bwk[i]=f2bf(wk[i]); bwv[i]=f2bf(wv[i]);
    unsigned short r = f2bf(rw[i]);
    brw[i]=r;
    int ri = i / DD, o = i % DD;
    brwt[o*DD + ri] = r;
  }
}

// bias in 16x16-tile layout: biasT[((b*32 + q>>4)*32 + k>>4)*256 + (q&15)*16 + (k&15)]
__global__ void bias_kernel(const int* __restrict__ mask, const float* __restrict__ adj,
                            const int* __restrict__ layer, unsigned short* __restrict__ biasT){
  float sc = 1.0f/(float)(layer[0]+1);
  int i = blockIdx.x*blockDim.x + threadIdx.x;
  const int n4 = (BB*SS*SS)/4;
  for (; i < n4; i += gridDim.x*blockDim.x){
    i32x4 m = ((const i32x4*)mask)[i];
    f32x4 a = ((const f32x4*)adj)[i];
    u16x4 r;
    #pragma unroll
    for (int j=0;j<4;j++) r[j] = m[j] ? f2bf(a[j]*sc) : f2bf(-1e9f);
    const int e  = i*4;
    const int bb = e >> 18;
    const int qq = (e >> 9) & 511;
    const int kk = e & 511;
    const int idx = (((bb*32 + (qq>>4))*32 + (kk>>4))<<8) + ((qq&15)<<4) + (kk&15);
    *(u16x4*)(biasT + idx) = r;
  }
}

// ---------------- GEMM bodies ----------------
#define BM 128
#define BN 128
#define BK 32

__device__ inline void gload_lds16(const unsigned short* g, unsigned short* l){
  __builtin_amdgcn_global_load_lds(
      (const __attribute__((address_space(1))) unsigned int*)g,
      (__attribute__((address_space(3))) unsigned int*)l, 16, 0, 0);
}

// core: computes acc[4][4] for C-tile (m0,n0) of A(16384xK=640) x W^T; dbuf LDS.
template<typename EPI>
__device__ inline void gemm_body(const unsigned short* __restrict__ A,
                                 const unsigned short* __restrict__ W,
                                 int m0, int n0, EPI&& epi)
{
  __shared__ unsigned short As[2][BM*BK];
  __shared__ unsigned short Ws[2][BN*BK];
  const int tid  = threadIdx.x;
  const int lane = tid & 63;
  const int wave = tid >> 6;
  const int wr   = (wave >> 1) * 64;
  const int wc   = (wave & 1) * 64;
  const int l15  = lane & 15;
  const int g    = lane >> 4;

  f32x4 acc[4][4];
  #pragma unroll
  for (int i=0;i<4;i++)
    #pragma unroll
    for (int j=0;j<4;j++){ f32x4 z = {0.f,0.f,0.f,0.f}; acc[i][j]=z; }

  const int srow = (lane >> 2);
  const int scol = (lane & 3) * 8;
  const unsigned short* Ag0 = A + (int64_t)(m0 + wave*32 + srow)*DD + scol;
  const unsigned short* Ag1 = A + (int64_t)(m0 + wave*32 + 16 + srow)*DD + scol;
  const unsigned short* Wg0 = W + (int64_t)(n0 + wave*32 + srow)*DD + scol;
  const unsigned short* Wg1 = W + (int64_t)(n0 + wave*32 + 16 + srow)*DD + scol;

  auto stage = [&](int buf, int k0){
    gload_lds16(Ag0 + k0, As[buf] + wave*1024);
    gload_lds16(Ag1 + k0, As[buf] + wave*1024 + 512);
    gload_lds16(Wg0 + k0, Ws[buf] + wave*1024);
    gload_lds16(Wg1 + k0, Ws[buf] + wave*1024 + 512);
  };

  stage(0, 0);
  int it = 0;
  for (int k0 = 0; k0 < DD; k0 += BK, it++){
    const int buf = it & 1;
    __syncthreads();               // stage(buf) landed; prior readers of buf^1 done
    if (k0 + BK < DD) stage(buf^1, k0 + BK);
    bf16x8 af[4], wf[4];
    #pragma unroll
    for (int m=0;m<4;m++) af[m] = *(const bf16x8*)&As[buf][(wr + m*16 + l15)*BK + g*8];
    #pragma unroll
    for (int n=0;n<4;n++) wf[n] = *(const bf16x8*)&Ws[buf][(wc + n*16 + l15)*BK + g*8];
    #pragma unroll
    for (int m=0;m<4;m++)
      #pragma unroll
      for (int n=0;n<4;n++)
        acc[m][n] = __builtin_amdgcn_mfma_f32_16x16x32_bf16(af[m], wf[n], acc[m][n], 0,0,0);
  }

  #pragma unroll
  for (int m=0;m<4;m++){
    const int rowbase = m0 + wr + m*16 + g*4;
    #pragma unroll
    for (int n=0;n<4;n++){
      const int col = n0 + wc + n*16 + l15;
      #pragma unroll
      for (int r=0;r<4;r++)
        epi(rowbase + r, col, acc[m][n][r]);
    }
  }
}

// merged QKV projection: grid (128, 15); y/5 selects {q,k,v}, y%5 selects n-tile
__global__ __launch_bounds__(256)
void qkv_gemm(const unsigned short* __restrict__ Xq, const unsigned short* __restrict__ Xk,
              const unsigned short* __restrict__ Xv,
              const unsigned short* __restrict__ bWq, const unsigned short* __restrict__ bWk,
              const unsigned short* __restrict__ bWv,
              const float* __restrict__ bq, const float* __restrict__ bk,
              const float* __restrict__ bv,
              unsigned short* __restrict__ qbuf, unsigned short* __restrict__ kbuf,
              unsigned short* __restrict__ vTbuf)
{
  const int y   = blockIdx.y;
  const int sel = y / 5;
  const int n0  = (y % 5) * BN;
  const int m0  = blockIdx.x * BM;
  const unsigned short* A = sel==0 ? Xq  : sel==1 ? Xk  : Xv;
  const unsigned short* W = sel==0 ? bWq : sel==1 ? bWk : bWv;
  const float*          bb= sel==0 ? bq  : sel==1 ? bk  : bv;
  unsigned short* outp    = sel==0 ? qbuf : kbuf;   // sel==2 handled below

  gemm_body(A, W, m0, n0, [&](int row, int col, float v){
    float val = v + bb[col];
    int b=row>>9, s=row&511, h=col>>6, dk=col&63;
    if (sel < 2)
      outp[(((int64_t)(b*HH + h))*SS + s)*DKK + dk] = f2bf(val);
    else
      vTbuf[(((int64_t)(b*HH + h))*DKK + dk)*SS + s] = f2bf(val);
  });
}

// routing GEMM: C = (A @ W^T) * scale, bf16 out [n,j]
__global__ __launch_bounds__(256)
void gemm_nt(const unsigned short* __restrict__ A, const unsigned short* __restrict__ W,
             unsigned short* __restrict__ outp, float scale)
{
  gemm_body(A, W, blockIdx.x*BM, blockIdx.y*BN, [&](int row, int col, float v){
    outp[(int64_t)row*DD + col] = f2bf(v*scale);
  });
}

// ---------------- attention ----------------
// block=(qt64,h,b), 4 waves x 16 q-rows. K/V staged via gload_lds (pre-swizzled
// global source -> XOR-swizzled LDS), double-buffered, shared by waves.
// Transposed-score mfma(K,Q); bias prefetched into regs one chunk ahead.
__global__ __launch_bounds__(256)
void attn_kernel(const unsigned short* __restrict__ qb, const unsigned short* __restrict__ kb,
                 const unsigned short* __restrict__ vT, const unsigned short* __restrict__ biasT,
                 unsigned short* __restrict__ xout)
{
  __shared__ unsigned short SH[20480];   // 40KB: K 2x8KB | V 2x8KB | P 4x2KB
  unsigned short* Kl = SH;               // [2][4096]
  unsigned short* Vl = SH + 8192;        // [2][4096]
  char* Pall = (char*)(SH + 16384);

  const int tid  = threadIdx.x;
  const int lane = tid & 63;
  const int wave = tid >> 6;
  const int l15  = lane & 15;
  const int g    = lane >> 4;

  const int qt = blockIdx.x;   // 0..7
  const int h  = blockIdx.y;   // 0..9
  const int b  = blockIdx.z;   // 0..31
  const int bh = b*HH + h;

  const unsigned short* Q  = qb + (int64_t)bh*SS*DKK;
  const unsigned short* K  = kb + (int64_t)bh*SS*DKK;
  const unsigned short* V  = vT + (int64_t)bh*DKK*SS;
  const unsigned short* Bt = biasT + (int64_t)((b*32 + qt*4 + wave)*32)*256
                           + l15*16 + g*4;

  const int q0 = qt*64 + wave*16;
  char* Pb = Pall + wave*2048;           // 16 rows x 128B

  const int srow8 = lane >> 3;
  const int sunit = (lane & 7) ^ (srow8 & 7);

  bf16x8 qf[2];
  #pragma unroll
  for (int ks=0; ks<2; ks++)
    qf[ks] = *(const bf16x8*)(Q + (q0 + l15)*DKK + ks*32 + g*8);

  auto stage = [&](int c, int buf){
    #pragma unroll
    for (int c2=0;c2<2;c2++){
      const int i = wave*2 + c2;                      // 0..7 across waves
      gload_lds16(K + (int64_t)(c*64 + i*8 + srow8)*DKK + sunit*8,
                  Kl + buf*4096 + i*512);
      gload_lds16(V + (int64_t)(i*8 + srow8)*SS + c*64 + sunit*8,
                  Vl + buf*4096 + i*512);
    }
  };

  float lsum = 0.f;
  f32x4 oacc[4];
  #pragma unroll
  for (int n=0;n<4;n++){ f32x4 z={0.f,0.f,0.f,0.f}; oacc[n]=z; }

  // prefetch chunk-0 bias into regs
  u16x4 bvc[4], bvn[4];
  #pragma unroll
  for (int j=0;j<4;j++) bvc[j] = *(const u16x4*)(Bt + j*256);

  stage(0, 0);
  for (int c = 0; c < 8; c++){
    const int buf = c & 1;
    __syncthreads();                     // stage(c) landed; buf^1 readers done
    if (c < 7){
      stage(c+1, buf^1);
      #pragma unroll
      for (int j=0;j<4;j++) bvn[j] = *(const u16x4*)(Bt + ((c+1)*4 + j)*256);
    }

    f32x4 sc[4];
    #pragma unroll
    for (int j=0;j<4;j++){ f32x4 z={0.f,0.f,0.f,0.f}; sc[j]=z; }
    #pragma unroll
    for (int ks=0; ks<2; ks++){
      #pragma unroll
      for (int j=0;j<4;j++){
        bf16x8 kf = *(const bf16x8*)((char*)(Kl + buf*4096)
                     + (j*16 + l15)*128 + (((ks*4+g) ^ (l15&7))*16));
        sc[j] = __builtin_amdgcn_mfma_f32_16x16x32_bf16(kf, qf[ks], sc[j], 0,0,0);
      }
    }
    // softmax partial: row=k=c*64+j*16+g*4+r, col=q=l15
    #pragma unroll
    for (int j=0;j<4;j++){
      float p[4];
      #pragma unroll
      for (int r=0;r<4;r++){
        float s = __builtin_fmaf(sc[j][r], 0.125f, bf2f(bvc[j][r]));
        p[r] = __expf(s - 8.0f);
        lsum += p[r];
      }
      unsigned int w0 = cvtpk_bf16(p[0], p[1]);
      unsigned int w1 = cvtpk_bf16(p[2], p[3]);
      const int kk = j*16 + g*4;
      const int sw = (kk >> 3) ^ (l15 & 7);
      u32x2 w; w[0]=w0; w[1]=w1;
      *(u32x2*)(Pb + l15*128 + sw*16 + (kk&7)*2) = w;
    }
    // PV for this chunk
    #pragma unroll
    for (int kt=0; kt<2; kt++){
      bf16x8 pf = *(const bf16x8*)(Pb + l15*128 + (((kt*4+g) ^ (l15&7))*16));
      #pragma unroll
      for (int n=0;n<4;n++){
        bf16x8 vf = *(const bf16x8*)((char*)(Vl + buf*4096)
                     + (n*16 + l15)*128 + (((kt*4+g) ^ (l15&7))*16));
        oacc[n] = __builtin_amdgcn_mfma_f32_16x16x32_bf16(pf, vf, oacc[n], 0,0,0);
      }
    }
    #pragma unroll
    for (int j=0;j<4;j++) bvc[j] = bvn[j];
  }

  lsum += __shfl_xor(lsum, 16);
  lsum += __shfl_xor(lsum, 32);
  const float inv = 1.0f / lsum;          // valid for q=l15
  float invr[4];
  #pragma unroll
  for (int r=0;r<4;r++) invr[r] = __shfl(inv, g*4 + r);

  #pragma unroll
  for (int n=0;n<4;n++){
    const int dk = n*16 + l15;
    #pragma unroll
    for (int r=0;r<4;r++){
      const int qrow = q0 + g*4 + r;
      const int ntok = b*SS + qrow;
      xout[(int64_t)ntok*DD + h*DKK + dk] = f2bf(oacc[n][r] * invr[r]);
    }
  }
}

// ---------------- routing elementwise ----------------
__global__ void squash_kernel(const unsigned short* __restrict__ sin,
                              unsigned short* __restrict__ bout,
                              float* __restrict__ fout, int final_out)
{
  const int widx = (blockIdx.x*blockDim.x + threadIdx.x) >> 6;
  const int lane = threadIdx.x & 63;
  if (widx >= NTOK) return;
  const unsigned short* row = sin + (int64_t)widx*DD;
  float v[10]; float sn = 0.f;
  #pragma unroll
  for (int i=0;i<10;i++){ v[i] = bf2f(row[i*64 + lane]); sn += v[i]*v[i]; }
  #pragma unroll
  for (int off=1; off<64; off<<=1) sn += __shfl_xor(sn, off);
  const float sc = (sn/(1.0f+sn)) * rsqrtf(sn + 1e-9f);
  if (final_out){
    float* o = fout + (int64_t)widx*DD;
    #pragma unroll
    for (int i=0;i<10;i++) o[i*64+lane] = v[i]*sc;
  } else {
    unsigned short* o = bout + (int64_t)widx*DD;
    #pragma unroll
    for (int i=0;i<10;i++) o[i*64+lane] = f2bf(v[i]*sc);
  }
}

__global__ void route_update(const unsigned short* __restrict__ x,
                             const unsigned short* __restrict__ gbuf,
                             float* __restrict__ logits,
                             unsigned short* __restrict__ xs, int first)
{
  const int widx = (blockIdx.x*blockDim.x + threadIdx.x) >> 6;
  const int lane = threadIdx.x & 63;
  if (widx >= NTOK) return;
  const unsigned short* xr = x + (int64_t)widx*DD;
  const unsigned short* gr = gbuf + (int64_t)widx*DD;
  float xv[10], dv[10];
  #pragma unroll
  for (int i=0;i<10;i++){
    xv[i] = bf2f(xr[i*64+lane]);
    dv[i] = xv[i]*bf2f(gr[i*64+lane]);
  }
  #pragma unroll
  for (int i=0;i<10;i++){
    float v = dv[i];
    #pragma unroll
    for (int off=1; off<64; off<<=1) v += __shfl_xor(v, off);
    dv[i] = v;
  }
  float* lrow = logits + widx*10;
  float lg[10];
  #pragma unroll
  for (int i=0;i<10;i++) lg[i] = first ? dv[i] : (lrow[i] + dv[i]);
  // static-index predicated stores (avoid runtime index -> scratch)
  #pragma unroll
  for (int i=0;i<10;i++) if (lane == i) lrow[i] = lg[i];
  float mx = lg[0];
  #pragma unroll
  for (int i=1;i<10;i++) mx = fmaxf(mx, lg[i]);
  float se = 0.f;
  #pragma unroll
  for (int i=0;i<10;i++){ lg[i] = __expf(lg[i]-mx); se += lg[i]; }
  const float inv = 1.0f/se;
  unsigned short* xo = xs + (int64_t)widx*DD;
  #pragma unroll
  for (int i=0;i<10;i++) xo[i*64+lane] = f2bf(xv[i]*lg[i]*inv);
}

// ---------------- launch ----------------
extern "C" void kernel_launch(void* const* d_in, const int* in_sizes, int n_in,
                              void* d_out, int out_size, void* d_ws, size_t ws_size,
                              hipStream_t stream)
{
  (void)in_sizes; (void)n_in; (void)out_size; (void)ws_size;
  const float* q    = (const float*)d_in[0];
  const float* k    = (const float*)d_in[1];
  const float* v    = (const float*)d_in[2];
  const int*   mask = (const int*)d_in[3];
  const float* adj  = (const float*)d_in[4];
  const int*   layer= (const int*)d_in[5];
  const float* Wq   = (const float*)d_in[6];
  const float* bq   = (const float*)d_in[7];
  const float* Wk   = (const float*)d_in[8];
  const float* bk   = (const float*)d_in[9];
  const float* Wv   = (const float*)d_in[10];
  const float* bv   = (const float*)d_in[11];
  const float* rw   = (const float*)d_in[12];

  char* ws = (char*)d_ws;
  size_t off = 0;
  auto alloc = [&](size_t sz)->char*{ char* p = ws + off; off += (sz + 255) & ~(size_t)255; return p; };
  const size_t SZX = (size_t)NTOK*DD*2;
  unsigned short* Xq    = (unsigned short*)alloc(SZX);
  unsigned short* Xk    = (unsigned short*)alloc(SZX);
  unsigned short* Xv    = (unsigned short*)alloc(SZX);
  unsigned short* bWq   = (unsigned short*)alloc((size_t)DD*DD*2);
  unsigned short* bWk   = (unsigned short*)alloc((size_t)DD*DD*2);
  unsigned short* bWv   = (unsigned short*)alloc((size_t)DD*DD*2);
  unsigned short* bRW   = (unsigned short*)alloc((size_t)DD*DD*2);
  unsigned short* bRWT  = (unsigned short*)alloc((size_t)DD*DD*2);
  unsigned short* qbuf  = (unsigned short*)alloc(SZX);
  unsigned short* kbuf  = (unsigned short*)alloc(SZX);
  unsigned short* vTbuf = (unsigned short*)alloc(SZX);
  unsigned short* biasb = (unsigned short*)alloc((size_t)BB*SS*SS*2);
  unsigned short* xsb   = (unsigned short*)alloc(SZX);
  float*          logit = (float*)alloc((size_t)NTOK*10*4);
  // aliases (provably dead at reuse time, stream-ordered):
  unsigned short* xout  = Xq;    // Xq dead after q-projection
  unsigned short* outit = Xk;    // Xk dead after k-projection
  unsigned short* gbuf  = Xv;    // Xv dead after v-projection
  unsigned short* sbuf  = qbuf;  // qbuf dead after attention

  convert_qkv<<<2048,256,0,stream>>>(q,k,v,Xq,Xk,Xv);
  convert_w<<<1600,256,0,stream>>>(Wq,Wk,Wv,rw,bWq,bWk,bWv,bRW,bRWT);
  bias_kernel<<<2048,256,0,stream>>>(mask,adj,layer,biasb);

  dim3 gq(NTOK/BM, 15);
  qkv_gemm<<<gq,256,0,stream>>>(Xq,Xk,Xv,bWq,bWk,bWv,bq,bk,bv,qbuf,kbuf,vTbuf);

  dim3 ga(8, HH, BB);
  attn_kernel<<<ga,256,0,stream>>>(qbuf,kbuf,vTbuf,biasb,xout);

  dim3 gg(NTOK/BM, DD/BN);
  // routing: it0 (uniform probs 1/10 folded into scale)
  gemm_nt<<<gg,256,0,stream>>>(xout,bRWT,sbuf,0.1f);
  squash_kernel<<<4096,256,0,stream>>>(sbuf,outit,nullptr,0);
  gemm_nt<<<gg,256,0,stream>>>(outit,bRW,gbuf,1.0f);
  route_update<<<4096,256,0,stream>>>(xout,gbuf,logit,xsb,1);
  // it1
  gemm_nt<<<gg,256,0,stream>>>(xsb,bRWT,sbuf,1.0f);
  squash_kernel<<<4096,256,0,stream>>>(sbuf,outit,nullptr,0);
  gemm_nt<<<gg,256,0,stream>>>(outit,bRW,gbuf,1.0f);
  route_update<<<4096,256,0,stream>>>(xout,gbuf,logit,xsb,0);
  // it2 (final)
  gemm_nt<<<gg,256,0,stream>>>(xsb,bRWT,sbuf,1.0f);
  squash_kernel<<<4096,256,0,stream>>>(sbuf,nullptr,(float*)d_out,1);
}